// Round 2
// baseline (619.476 us; speedup 1.0000x reference)
//
#include <hip/hip_runtime.h>

#define NPTS 524288
#define TBL_MASK ((1u << 19) - 1u)
#define BLK 128

__device__ __forceinline__ float sstep(float t) { return t * t * (3.0f - 2.0f * t); }

__global__ __launch_bounds__(BLK)
void nerf_fwd(const float* __restrict__ x,
              const float* __restrict__ v,
              const float* __restrict__ table,
              const float* __restrict__ dw1, const float* __restrict__ db1,
              const float* __restrict__ dw2, const float* __restrict__ db2,
              const float* __restrict__ rw1, const float* __restrict__ rb1,
              const float* __restrict__ rw2, const float* __restrict__ rb2,
              float* __restrict__ out)
{
    // Per-thread-column activation scratchpad: buf[row*BLK + tid].
    // Each thread touches only its own column -> no barriers needed.
    // Bank pattern: addr/4 % 32 == tid % 32 -> 2-way aliasing (free on CDNA4).
    __shared__ float buf[73 * BLK];

    const int tid = threadIdx.x;
    const int gi  = blockIdx.x * BLK + tid;

    const float x0 = x[3 * gi + 0], x1 = x[3 * gi + 1], x2 = x[3 * gi + 2];
    const float v0 = v[3 * gi + 0], v1 = v[3 * gi + 1], v2 = v[3 * gi + 2];

    // ---- encoding rows 0..2: xyz ----
    buf[0 * BLK + tid] = x0;
    buf[1 * BLK + tid] = x1;
    buf[2 * BLK + tid] = x2;

    // ---- rows 3..38: fourier, freqs 2^0..2^5 (exact fp32 scaling) ----
    {
        const float a[3] = {x0, x1, x2};
        #pragma unroll
        for (int d = 0; d < 3; ++d) {
            #pragma unroll
            for (int f = 0; f < 6; ++f) {
                const float ang = a[d] * (float)(1 << f);
                buf[(3 + d * 12 + f) * BLK + tid]     = __sinf(ang);
                buf[(3 + d * 12 + 6 + f) * BLK + tid] = __cosf(ang);
            }
        }
    }

    // ---- rows 39..46: hashgrid levels 0..3 (progressive mask kills 4..15) ----
    {
        const float x01_0 = (x0 + 1.0f) * 0.5f;
        const float x01_1 = (x1 + 1.0f) * 0.5f;
        const float x01_2 = (x2 + 1.0f) * 0.5f;
        const float resf[4] = {33.0f, 43.0f, 56.0f, 74.0f};
        #pragma unroll
        for (int lv = 0; lv < 4; ++lv) {
            const float px = x01_0 * resf[lv], py = x01_1 * resf[lv], pz = x01_2 * resf[lv];
            const float fx = floorf(px), fy = floorf(py), fz = floorf(pz);
            const float wx = sstep(px - fx), wy = sstep(py - fy), wz = sstep(pz - fz);
            const unsigned cx = (unsigned)fx, cy = (unsigned)fy, cz = (unsigned)fz;
            float g0 = 0.0f, g1 = 0.0f;
            #pragma unroll
            for (int c = 0; c < 8; ++c) {
                const unsigned hx = cx + (c & 1);
                const unsigned hy = cy + ((c >> 1) & 1);
                const unsigned hz = cz + ((c >> 2) & 1);
                const unsigned hh = (hx ^ (hy * 2654435761u) ^ (hz * 805459861u)) & TBL_MASK;
                const float2 tv = *reinterpret_cast<const float2*>(table + ((unsigned)lv * (TBL_MASK + 1u) + hh) * 2u);
                const float cw = ((c & 1) ? wx : 1.0f - wx) *
                                 ((c & 2) ? wy : 1.0f - wy) *
                                 ((c & 4) ? wz : 1.0f - wz);
                g0 = fmaf(cw, tv.x, g0);
                g1 = fmaf(cw, tv.y, g1);
            }
            buf[(39 + 2 * lv + 0) * BLK + tid] = g0;
            buf[(39 + 2 * lv + 1) * BLK + tid] = g1;
        }
    }

    // ---- layer 1: 47 -> 64, relu. Outer-product over inputs; weights are
    // wave-uniform scalar loads (natural row-major), accumulators static.
    float h[64];
    #pragma unroll
    for (int j = 0; j < 64; ++j) h[j] = db1[j];
    #pragma unroll 2
    for (int i = 0; i < 47; ++i) {
        const float xi = buf[i * BLK + tid];
        const float* __restrict__ wrow = dw1 + i * 64;
        #pragma unroll
        for (int j = 0; j < 64; ++j) h[j] = fmaf(xi, wrow[j], h[j]);
    }
    #pragma unroll
    for (int j = 0; j < 64; ++j) buf[j * BLK + tid] = fmaxf(h[j], 0.0f);

    // ---- layer 2: 64 -> 65 (col 0 -> sigma via exp, cols 1..64 -> relu feat) ----
    float ri[65];
    #pragma unroll
    for (int k = 0; k < 65; ++k) ri[k] = db2[k];
    #pragma unroll 2
    for (int j = 0; j < 64; ++j) {
        const float hj = buf[j * BLK + tid];
        const float* __restrict__ wrow = dw2 + j * 65;
        #pragma unroll
        for (int k = 0; k < 65; ++k) ri[k] = fmaf(hj, wrow[k], ri[k]);
    }
    out[gi] = __expf(ri[0]);   // sigma

    // rgb input: rows 0..63 = relu(feat), rows 64..72 = sh3(v)
    #pragma unroll
    for (int k = 0; k < 64; ++k) buf[k * BLK + tid] = fmaxf(ri[k + 1], 0.0f);
    buf[64 * BLK + tid] = 0.28209479177387814f;
    buf[65 * BLK + tid] = -0.4886025119029199f * v1;
    buf[66 * BLK + tid] =  0.4886025119029199f * v2;
    buf[67 * BLK + tid] = -0.4886025119029199f * v0;
    buf[68 * BLK + tid] =  1.0925484305920792f * v0 * v1;
    buf[69 * BLK + tid] = -1.0925484305920792f * v1 * v2;
    buf[70 * BLK + tid] =  0.9461746957575601f * v2 * v2 - 0.31539156525252005f;
    buf[71 * BLK + tid] = -1.0925484305920792f * v0 * v2;
    buf[72 * BLK + tid] =  0.5462742152960396f * (v0 * v0 - v1 * v1);

    // ---- layer 3: 73 -> 64, relu ----
    float hr[64];
    #pragma unroll
    for (int j = 0; j < 64; ++j) hr[j] = rb1[j];
    #pragma unroll 2
    for (int i = 0; i < 73; ++i) {
        const float ti = buf[i * BLK + tid];
        const float* __restrict__ wrow = rw1 + i * 64;
        #pragma unroll
        for (int j = 0; j < 64; ++j) hr[j] = fmaf(ti, wrow[j], hr[j]);
    }

    // ---- layer 4: 64 -> 3, sigmoid (static unroll; hr stays in regs) ----
    float r0 = rb2[0], r1 = rb2[1], r2 = rb2[2];
    #pragma unroll
    for (int j = 0; j < 64; ++j) {
        const float hj = fmaxf(hr[j], 0.0f);
        r0 = fmaf(hj, rw2[3 * j + 0], r0);
        r1 = fmaf(hj, rw2[3 * j + 1], r1);
        r2 = fmaf(hj, rw2[3 * j + 2], r2);
    }
    out[NPTS + 3 * gi + 0] = 1.0f / (1.0f + __expf(-r0));
    out[NPTS + 3 * gi + 1] = 1.0f / (1.0f + __expf(-r1));
    out[NPTS + 3 * gi + 2] = 1.0f / (1.0f + __expf(-r2));
}

extern "C" void kernel_launch(void* const* d_in, const int* in_sizes, int n_in,
                              void* d_out, int out_size, void* d_ws, size_t ws_size,
                              hipStream_t stream) {
    const float* x     = (const float*)d_in[0];
    const float* v     = (const float*)d_in[1];
    // d_in[2] = o, unused by the forward pass
    const float* table = (const float*)d_in[3];
    const float* dw1   = (const float*)d_in[4];
    const float* db1   = (const float*)d_in[5];
    const float* dw2   = (const float*)d_in[6];
    const float* db2   = (const float*)d_in[7];
    const float* rw1   = (const float*)d_in[8];
    const float* rb1   = (const float*)d_in[9];
    const float* rw2   = (const float*)d_in[10];
    const float* rb2   = (const float*)d_in[11];
    float* out = (float*)d_out;

    dim3 grid(NPTS / BLK), block(BLK);
    hipLaunchKernelGGL(nerf_fwd, grid, block, 0, stream,
                       x, v, table, dw1, db1, dw2, db2, rw1, rb1, rw2, rb2, out);
}

// Round 3
// 295.027 us; speedup vs baseline: 2.0997x; 2.0997x over previous
//
#include <hip/hip_runtime.h>

#define NPTS 524288
#define TBLM ((1u << 19) - 1u)
#define PB   128          // points per block
#define THR  256

typedef _Float16 half8  __attribute__((ext_vector_type(8)));
typedef _Float16 half4v __attribute__((ext_vector_type(4)));
typedef float    f32x4  __attribute__((ext_vector_type(4)));

__device__ __forceinline__ float sstep(float t) { return t * t * (3.0f - 2.0f * t); }

__global__ __launch_bounds__(THR, 2)
void nerf_fwd(const float* __restrict__ x,
              const float* __restrict__ v,
              const float* __restrict__ table,
              const float* __restrict__ dw1, const float* __restrict__ db1,
              const float* __restrict__ dw2, const float* __restrict__ db2,
              const float* __restrict__ rw1, const float* __restrict__ rb1,
              const float* __restrict__ rw2, const float* __restrict__ rb2,
              float* __restrict__ out)
{
    // One weight buffer, re-staged per layer (max 64x104 = 6656 halves).
    __shared__ __align__(16) _Float16 wt[64 * 104];
    __shared__ __align__(16) float    sb[80];
    // Activation ping-pong. aBuf stride 104 (K<=96 +8 pad), bBuf stride 72 (K=64 +8).
    __shared__ __align__(16) _Float16 aBuf[PB * 104];
    __shared__ __align__(16) _Float16 bBuf[PB * 72];

    const int tid  = threadIdx.x;
    const int lane = tid & 63;
    const int wv   = tid >> 6;       // 4 waves; wave owns point-tiles 2wv, 2wv+1
    const int lr   = lane & 15;      // tile row (A) / point col (B,C)
    const int lg   = lane >> 4;      // lane group 0..3

    // ---- stage WT1: wt[j][k] = dw1[k][j], K pad 47->64+8, rows 64 ----
    for (int idx = tid; idx < 64 * 72; idx += THR) {
        int j = idx / 72, k = idx - j * 72;
        wt[idx] = (k < 47) ? (_Float16)dw1[k * 64 + j] : (_Float16)0.f;
    }
    if (tid < 64) sb[tid] = db1[tid];

    // ---- encoding: 2 threads per point ----
    {
        const int p  = tid & (PB - 1);
        const int gi = blockIdx.x * PB + p;
        const float x0 = x[3 * gi + 0], x1 = x[3 * gi + 1], x2 = x[3 * gi + 2];
        _Float16* row = aBuf + p * 104;
        if (tid < PB) {
            // xyz + fourier + zero-pad cols 47..63
            row[0] = (_Float16)x0; row[1] = (_Float16)x1; row[2] = (_Float16)x2;
            const float a[3] = {x0, x1, x2};
            #pragma unroll
            for (int d = 0; d < 3; ++d)
                #pragma unroll
                for (int f = 0; f < 6; ++f) {
                    const float ang = a[d] * (float)(1 << f);
                    row[3 + d * 12 + f]     = (_Float16)__sinf(ang);
                    row[3 + d * 12 + 6 + f] = (_Float16)__cosf(ang);
                }
            for (int c = 47; c < 64; ++c) row[c] = (_Float16)0.f;
        } else {
            // hashgrid levels 0..3 (progressive mask kills 4..15) -> cols 39..46
            const float u0 = (x0 + 1.0f) * 0.5f, u1 = (x1 + 1.0f) * 0.5f, u2 = (x2 + 1.0f) * 0.5f;
            const float resf[4] = {33.0f, 43.0f, 56.0f, 74.0f};
            #pragma unroll
            for (int lv = 0; lv < 4; ++lv) {
                const float px = u0 * resf[lv], py = u1 * resf[lv], pz = u2 * resf[lv];
                const float fx = floorf(px), fy = floorf(py), fz = floorf(pz);
                const float wx = sstep(px - fx), wy = sstep(py - fy), wz = sstep(pz - fz);
                const unsigned cx = (unsigned)fx, cy = (unsigned)fy, cz = (unsigned)fz;
                float g0 = 0.f, g1 = 0.f;
                #pragma unroll
                for (int c = 0; c < 8; ++c) {
                    const unsigned hx = cx + (c & 1);
                    const unsigned hy = cy + ((c >> 1) & 1);
                    const unsigned hz = cz + ((c >> 2) & 1);
                    const unsigned hh = (hx ^ (hy * 2654435761u) ^ (hz * 805459861u)) & TBLM;
                    const float2 tv = *reinterpret_cast<const float2*>(table + ((unsigned)lv * (TBLM + 1u) + hh) * 2u);
                    const float cw = ((c & 1) ? wx : 1.0f - wx) *
                                     ((c & 2) ? wy : 1.0f - wy) *
                                     ((c & 4) ? wz : 1.0f - wz);
                    g0 = fmaf(cw, tv.x, g0);
                    g1 = fmaf(cw, tv.y, g1);
                }
                row[39 + 2 * lv + 0] = (_Float16)g0;
                row[39 + 2 * lv + 1] = (_Float16)g1;
            }
            // sh3(v) -> cols 65..73 (L3 input; col 0 is zero-weighted), zeros 74..95
            const float v0 = v[3 * gi + 0], v1 = v[3 * gi + 1], v2 = v[3 * gi + 2];
            row[65] = (_Float16)0.28209479177387814f;
            row[66] = (_Float16)(-0.4886025119029199f * v1);
            row[67] = (_Float16)( 0.4886025119029199f * v2);
            row[68] = (_Float16)(-0.4886025119029199f * v0);
            row[69] = (_Float16)( 1.0925484305920792f * v0 * v1);
            row[70] = (_Float16)(-1.0925484305920792f * v1 * v2);
            row[71] = (_Float16)( 0.9461746957575601f * v2 * v2 - 0.31539156525252005f);
            row[72] = (_Float16)(-1.0925484305920792f * v0 * v2);
            row[73] = (_Float16)( 0.5462742152960396f * (v0 * v0 - v1 * v1));
            for (int c = 74; c < 96; ++c) row[c] = (_Float16)0.f;
        }
    }
    __syncthreads();

    // ================= L1: 47(pad64) -> 64, relu.  A=WT1[64x72], B=aBuf ===========
    {
        half8 A[4][2];
        #pragma unroll
        for (int m = 0; m < 4; ++m)
            #pragma unroll
            for (int kc = 0; kc < 2; ++kc)
                A[m][kc] = *(const half8*)&wt[(16 * m + lr) * 72 + kc * 32 + lg * 8];
        #pragma unroll
        for (int n = 0; n < 2; ++n) {
            const int pt = (2 * wv + n) * 16 + lr;
            const half8 B0 = *(const half8*)&aBuf[pt * 104 + 0 * 32 + lg * 8];
            const half8 B1 = *(const half8*)&aBuf[pt * 104 + 1 * 32 + lg * 8];
            #pragma unroll
            for (int m = 0; m < 4; ++m) {
                f32x4 c = *(const f32x4*)&sb[16 * m + 4 * lg];
                c = __builtin_amdgcn_mfma_f32_16x16x32_f16(A[m][0], B0, c, 0, 0, 0);
                c = __builtin_amdgcn_mfma_f32_16x16x32_f16(A[m][1], B1, c, 0, 0, 0);
                half4v o4;
                o4[0] = (_Float16)fmaxf(c[0], 0.f);
                o4[1] = (_Float16)fmaxf(c[1], 0.f);
                o4[2] = (_Float16)fmaxf(c[2], 0.f);
                o4[3] = (_Float16)fmaxf(c[3], 0.f);
                *(half4v*)&bBuf[pt * 72 + 16 * m + 4 * lg] = o4;
            }
        }
    }
    __syncthreads();

    // ================= L2: 64 -> 65 (row0 sigma, 1..64 feat). A=WT2[80x72] ========
    for (int idx = tid; idx < 80 * 72; idx += THR) {
        int r = idx / 72, k = idx - r * 72;
        wt[idx] = (k < 64 && r < 65) ? (_Float16)dw2[k * 65 + r] : (_Float16)0.f;
    }
    if (tid < 80) sb[tid] = (tid < 65) ? db2[tid] : 0.f;
    __syncthreads();
    {
        half8 A[5][2];
        #pragma unroll
        for (int m = 0; m < 5; ++m)
            #pragma unroll
            for (int kc = 0; kc < 2; ++kc)
                A[m][kc] = *(const half8*)&wt[(16 * m + lr) * 72 + kc * 32 + lg * 8];
        #pragma unroll
        for (int n = 0; n < 2; ++n) {
            const int pt = (2 * wv + n) * 16 + lr;
            const half8 B0 = *(const half8*)&bBuf[pt * 72 + 0 * 32 + lg * 8];
            const half8 B1 = *(const half8*)&bBuf[pt * 72 + 1 * 32 + lg * 8];
            #pragma unroll
            for (int m = 0; m < 5; ++m) {
                f32x4 c = *(const f32x4*)&sb[16 * m + 4 * lg];
                c = __builtin_amdgcn_mfma_f32_16x16x32_f16(A[m][0], B0, c, 0, 0, 0);
                c = __builtin_amdgcn_mfma_f32_16x16x32_f16(A[m][1], B1, c, 0, 0, 0);
                #pragma unroll
                for (int r = 0; r < 4; ++r) {
                    const int rw = 16 * m + 4 * lg + r;
                    if (rw == 0)
                        out[blockIdx.x * PB + pt] = __expf(c[r]);          // sigma
                    else if (rw <= 64)
                        aBuf[pt * 104 + rw] = (_Float16)fmaxf(c[r], 0.f);  // feat
                }
            }
        }
    }
    __syncthreads();

    // ================= L3: 74(pad96) -> 64, relu. A=WT3[64x104] ===================
    for (int idx = tid; idx < 64 * 104; idx += THR) {
        int j = idx / 104, cc = idx - j * 104;
        wt[idx] = (cc >= 1 && cc <= 73) ? (_Float16)rw1[(cc - 1) * 64 + j] : (_Float16)0.f;
    }
    if (tid < 64) sb[tid] = rb1[tid];
    __syncthreads();
    {
        half8 A[4][3];
        #pragma unroll
        for (int m = 0; m < 4; ++m)
            #pragma unroll
            for (int kc = 0; kc < 3; ++kc)
                A[m][kc] = *(const half8*)&wt[(16 * m + lr) * 104 + kc * 32 + lg * 8];
        #pragma unroll
        for (int n = 0; n < 2; ++n) {
            const int pt = (2 * wv + n) * 16 + lr;
            const half8 B0 = *(const half8*)&aBuf[pt * 104 + 0 * 32 + lg * 8];
            const half8 B1 = *(const half8*)&aBuf[pt * 104 + 1 * 32 + lg * 8];
            const half8 B2 = *(const half8*)&aBuf[pt * 104 + 2 * 32 + lg * 8];
            #pragma unroll
            for (int m = 0; m < 4; ++m) {
                f32x4 c = *(const f32x4*)&sb[16 * m + 4 * lg];
                c = __builtin_amdgcn_mfma_f32_16x16x32_f16(A[m][0], B0, c, 0, 0, 0);
                c = __builtin_amdgcn_mfma_f32_16x16x32_f16(A[m][1], B1, c, 0, 0, 0);
                c = __builtin_amdgcn_mfma_f32_16x16x32_f16(A[m][2], B2, c, 0, 0, 0);
                half4v o4;
                o4[0] = (_Float16)fmaxf(c[0], 0.f);
                o4[1] = (_Float16)fmaxf(c[1], 0.f);
                o4[2] = (_Float16)fmaxf(c[2], 0.f);
                o4[3] = (_Float16)fmaxf(c[3], 0.f);
                *(half4v*)&bBuf[pt * 72 + 16 * m + 4 * lg] = o4;
            }
        }
    }
    __syncthreads();

    // ================= L4: 64 -> 3, sigmoid. A=WT4[16x72] =========================
    for (int idx = tid; idx < 16 * 72; idx += THR) {
        int o = idx / 72, k = idx - o * 72;
        wt[idx] = (o < 3 && k < 64) ? (_Float16)rw2[k * 3 + o] : (_Float16)0.f;
    }
    if (tid < 16) sb[tid] = (tid < 3) ? rb2[tid] : 0.f;
    __syncthreads();
    {
        half8 A0 = *(const half8*)&wt[lr * 72 + 0 * 32 + lg * 8];
        half8 A1 = *(const half8*)&wt[lr * 72 + 1 * 32 + lg * 8];
        #pragma unroll
        for (int n = 0; n < 2; ++n) {
            const int pt = (2 * wv + n) * 16 + lr;
            const half8 B0 = *(const half8*)&bBuf[pt * 72 + 0 * 32 + lg * 8];
            const half8 B1 = *(const half8*)&bBuf[pt * 72 + 1 * 32 + lg * 8];
            f32x4 c = *(const f32x4*)&sb[4 * lg];
            c = __builtin_amdgcn_mfma_f32_16x16x32_f16(A0, B0, c, 0, 0, 0);
            c = __builtin_amdgcn_mfma_f32_16x16x32_f16(A1, B1, c, 0, 0, 0);
            if (lg == 0) {
                const int gpt = blockIdx.x * PB + pt;
                #pragma unroll
                for (int r = 0; r < 3; ++r)
                    out[NPTS + 3 * gpt + r] = 1.0f / (1.0f + __expf(-c[r]));
            }
        }
    }
}

extern "C" void kernel_launch(void* const* d_in, const int* in_sizes, int n_in,
                              void* d_out, int out_size, void* d_ws, size_t ws_size,
                              hipStream_t stream) {
    const float* x     = (const float*)d_in[0];
    const float* v     = (const float*)d_in[1];
    // d_in[2] = o, unused by the forward pass
    const float* table = (const float*)d_in[3];
    const float* dw1   = (const float*)d_in[4];
    const float* db1   = (const float*)d_in[5];
    const float* dw2   = (const float*)d_in[6];
    const float* db2   = (const float*)d_in[7];
    const float* rw1   = (const float*)d_in[8];
    const float* rb1   = (const float*)d_in[9];
    const float* rw2   = (const float*)d_in[10];
    const float* rb2   = (const float*)d_in[11];
    float* out = (float*)d_out;

    dim3 grid(NPTS / PB), block(THR);
    hipLaunchKernelGGL(nerf_fwd, grid, block, 0, stream,
                       x, v, table, dw1, db1, dw2, db2, rw1, rb1, rw2, rb2, out);
}

// Round 4
// 191.610 us; speedup vs baseline: 3.2330x; 1.5397x over previous
//
#include <hip/hip_runtime.h>

#define NPTS   524288
#define TBLM   ((1u << 19) - 1u)
#define THR    256
#define CHUNK  128
#define CHUNKS 4
#define GRID   (NPTS / (CHUNK * CHUNKS))   // 1024

typedef _Float16 half8  __attribute__((ext_vector_type(8)));
typedef _Float16 half4v __attribute__((ext_vector_type(4)));
typedef float    f32x4  __attribute__((ext_vector_type(4)));

// d_ws layout (halves): W1 frags [m4][kc2][lane64][j8] @0 (4096)
//                       W2 frags [m5][kc2][lane][j]   @4096 (5120)
//                       W3 frags [m4][kc3][lane][j]   @9216 (6144)
//                       W4 frags [kc2][lane][j]       @15360 (1024)
// floats @byte 32768: b1[64], b2[80], b3[64], b4[16]  (224 floats)
// total bytes: 33664

__global__ __launch_bounds__(256)
void prep(const float* __restrict__ dw1, const float* __restrict__ db1,
          const float* __restrict__ dw2, const float* __restrict__ db2,
          const float* __restrict__ rw1, const float* __restrict__ rb1,
          const float* __restrict__ rw2, const float* __restrict__ rb2,
          void* __restrict__ ws)
{
    const int t = blockIdx.x * 256 + threadIdx.x;
    if (t < 16384) {
        float w = 0.0f;
        if (t < 4096) {                       // W1: k' permuted (39 dead, grid at 40..47)
            const int u = t, mkc = u >> 9, m = mkc >> 1, kc = mkc & 1;
            const int lane = (u >> 3) & 63, j = u & 7;
            const int row = 16 * m + (lane & 15);
            const int kp  = kc * 32 + (lane >> 4) * 8 + j;
            if (kp < 39)      w = dw1[kp * 64 + row];
            else if (kp == 39) w = 0.0f;
            else if (kp < 48) w = dw1[(kp - 1) * 64 + row];
        } else if (t < 9216) {                // W2
            const int u = t - 4096, mkc = u >> 9, m = mkc >> 1, kc = mkc & 1;
            const int lane = (u >> 3) & 63, j = u & 7;
            const int row = 16 * m + (lane & 15);
            const int k   = kc * 32 + (lane >> 4) * 8 + j;
            if (row < 65) w = dw2[k * 65 + row];
        } else if (t < 15360) {               // W3: col0 dead, feat@1..64, sh3@65..73
            const int u = t - 9216, mkc = u >> 9, m = mkc / 3, kc = mkc - 3 * m;
            const int lane = (u >> 3) & 63, j = u & 7;
            const int row = 16 * m + (lane & 15);
            const int kp  = kc * 32 + (lane >> 4) * 8 + j;
            if (kp >= 1 && kp <= 73) w = rw1[(kp - 1) * 64 + row];
        } else {                              // W4
            const int u = t - 15360, kc = u >> 9;
            const int lane = (u >> 3) & 63, j = u & 7;
            const int row = lane & 15;
            const int k   = kc * 32 + (lane >> 4) * 8 + j;
            if (row < 3) w = rw2[k * 3 + row];
        }
        ((_Float16*)ws)[t] = (_Float16)w;
    } else if (t < 16384 + 224) {
        const int u = t - 16384;
        float b = 0.0f;
        if (u < 64)        b = db1[u];
        else if (u < 144)  { const int r = u - 64;  if (r < 65) b = db2[r]; }
        else if (u < 208)  b = rb1[u - 144];
        else               { const int r = u - 208; if (r < 3)  b = rb2[r]; }
        ((float*)((char*)ws + 32768))[u] = b;
    }
}

__device__ __forceinline__ float sstep(float t) { return t * t * (3.0f - 2.0f * t); }

__global__ __launch_bounds__(THR, 2)
void nerf_fwd(const float* __restrict__ x,
              const float* __restrict__ v,
              const float* __restrict__ table,
              const float* __restrict__ ws,
              float* __restrict__ out)
{
    // LDS: [0,32768) wt halves (frag order) ; [32768,33664) biases f32 ;
    //      [33664,60288) aBuf 128x104 f16  ; [60288,78720) bBuf 128x72 f16
    __shared__ __align__(16) unsigned char smem[78720];
    _Float16* wt    = (_Float16*)smem;
    float*    sbias = (float*)(smem + 32768);
    _Float16* aB    = (_Float16*)(smem + 33664);
    _Float16* bB    = (_Float16*)(smem + 60288);

    const int tid  = threadIdx.x;
    const int lane = tid & 63;
    const int wv   = tid >> 6;
    const int lr   = lane & 15;
    const int lg   = lane >> 4;

    // ---- stage weights+biases: one linear coalesced copy (2104 uint4) ----
    {
        const uint4* src = (const uint4*)ws;
        uint4* dst = (uint4*)smem;
        #pragma unroll
        for (int i = 0; i < 9; ++i) {
            const int idx = tid + i * THR;
            if (idx < 2104) dst[idx] = src[idx];
        }
    }
    __syncthreads();   // the only barrier: wt/sbias read-only afterwards

    const int gi0 = blockIdx.x * (CHUNK * CHUNKS);

    for (int c = 0; c < CHUNKS; ++c) {
        const int cbase = gi0 + c * CHUNK;

        // ================= encode (lane pairs; all rows wave-private) ==========
        {
            const int p  = (wv << 5) + (lane >> 1);
            const int gi = cbase + p;
            _Float16* row = aB + p * 104;
            const float x0 = x[3 * gi + 0], x1 = x[3 * gi + 1], x2 = x[3 * gi + 2];
            if (lane & 1) {
                // ---- hash levels 0..3 -> cols 40..47 ----
                const float u0 = (x0 + 1.0f) * 0.5f, u1 = (x1 + 1.0f) * 0.5f, u2 = (x2 + 1.0f) * 0.5f;
                const float resf[4] = {33.0f, 43.0f, 56.0f, 74.0f};
                float g[8];
                #pragma unroll
                for (int lv = 0; lv < 4; ++lv) {
                    const float px = u0 * resf[lv], py = u1 * resf[lv], pz = u2 * resf[lv];
                    const float fx = floorf(px), fy = floorf(py), fz = floorf(pz);
                    const float wx = sstep(px - fx), wy = sstep(py - fy), wz = sstep(pz - fz);
                    const unsigned cx = (unsigned)fx, cy = (unsigned)fy, cz = (unsigned)fz;
                    float g0 = 0.f, g1 = 0.f;
                    #pragma unroll
                    for (int cc = 0; cc < 8; ++cc) {
                        const unsigned hx = cx + (cc & 1);
                        const unsigned hy = cy + ((cc >> 1) & 1);
                        const unsigned hz = cz + ((cc >> 2) & 1);
                        const unsigned hh = (hx ^ (hy * 2654435761u) ^ (hz * 805459861u)) & TBLM;
                        const float2 tv = *reinterpret_cast<const float2*>(
                            table + ((unsigned)lv * (TBLM + 1u) + hh) * 2u);
                        const float cw = ((cc & 1) ? wx : 1.0f - wx) *
                                         ((cc & 2) ? wy : 1.0f - wy) *
                                         ((cc & 4) ? wz : 1.0f - wz);
                        g0 = fmaf(cw, tv.x, g0);
                        g1 = fmaf(cw, tv.y, g1);
                    }
                    g[2 * lv]     = g0;
                    g[2 * lv + 1] = g1;
                }
                half8 h;
                #pragma unroll
                for (int i = 0; i < 8; ++i) h[i] = (_Float16)g[i];
                *(half8*)(row + 40) = h;
                // ---- sh3 -> cols 65..73 (col64 placeholder, L2 overwrites) ----
                const float v0 = v[3 * gi + 0], v1 = v[3 * gi + 1], v2 = v[3 * gi + 2];
                float sh[9];
                sh[0] = 0.28209479177387814f;
                sh[1] = -0.4886025119029199f * v1;
                sh[2] =  0.4886025119029199f * v2;
                sh[3] = -0.4886025119029199f * v0;
                sh[4] =  1.0925484305920792f * v0 * v1;
                sh[5] = -1.0925484305920792f * v1 * v2;
                sh[6] =  0.9461746957575601f * v2 * v2 - 0.31539156525252005f;
                sh[7] = -1.0925484305920792f * v0 * v2;
                sh[8] =  0.5462742152960396f * (v0 * v0 - v1 * v1);
                half8 s0, s1, z;
                s0[0] = (_Float16)0.f;
                #pragma unroll
                for (int i = 0; i < 7; ++i) s0[i + 1] = (_Float16)sh[i];
                s1[0] = (_Float16)sh[7]; s1[1] = (_Float16)sh[8];
                #pragma unroll
                for (int i = 2; i < 8; ++i) s1[i] = (_Float16)0.f;
                #pragma unroll
                for (int i = 0; i < 8; ++i) z[i] = (_Float16)0.f;
                *(half8*)(row + 64) = s0;
                *(half8*)(row + 72) = s1;
                *(half8*)(row + 80) = z;
                *(half8*)(row + 88) = z;
            } else {
                // ---- xyz + fourier -> cols 0..38 (39 dead=0), zeros 48..63 ----
                float e[40];
                e[0] = x0; e[1] = x1; e[2] = x2;
                const float a[3] = {x0, x1, x2};
                #pragma unroll
                for (int d = 0; d < 3; ++d)
                    #pragma unroll
                    for (int f = 0; f < 6; ++f) {
                        const float ang = a[d] * (float)(1 << f);
                        e[3 + d * 12 + f]     = __sinf(ang);
                        e[3 + d * 12 + 6 + f] = __cosf(ang);
                    }
                e[39] = 0.0f;
                #pragma unroll
                for (int chk = 0; chk < 5; ++chk) {
                    half8 h;
                    #pragma unroll
                    for (int i = 0; i < 8; ++i) h[i] = (_Float16)e[chk * 8 + i];
                    *(half8*)(row + chk * 8) = h;
                }
                half8 z;
                #pragma unroll
                for (int i = 0; i < 8; ++i) z[i] = (_Float16)0.f;
                *(half8*)(row + 48) = z;
                *(half8*)(row + 56) = z;
            }
        }

        // ================= L1: 64 -> 64, relu  (A frags from LDS wt) ===========
        {
            half8 A[4][2];
            #pragma unroll
            for (int m = 0; m < 4; ++m)
                #pragma unroll
                for (int kc = 0; kc < 2; ++kc)
                    A[m][kc] = *(const half8*)(wt + (m * 2 + kc) * 512 + lane * 8);
            #pragma unroll
            for (int n = 0; n < 2; ++n) {
                const int pt = (wv << 5) + (n << 4) + lr;
                const half8 B0 = *(const half8*)(aB + pt * 104 + 0 * 32 + lg * 8);
                const half8 B1 = *(const half8*)(aB + pt * 104 + 1 * 32 + lg * 8);
                #pragma unroll
                for (int m = 0; m < 4; ++m) {
                    f32x4 cr = *(const f32x4*)(sbias + 0 + m * 16 + 4 * lg);
                    cr = __builtin_amdgcn_mfma_f32_16x16x32_f16(A[m][0], B0, cr, 0, 0, 0);
                    cr = __builtin_amdgcn_mfma_f32_16x16x32_f16(A[m][1], B1, cr, 0, 0, 0);
                    half4v o4;
                    #pragma unroll
                    for (int r = 0; r < 4; ++r) o4[r] = (_Float16)fmaxf(cr[r], 0.f);
                    *(half4v*)(bB + pt * 72 + 16 * m + 4 * lg) = o4;
                }
            }
        }

        // ================= L2: 64 -> 65 (sigma row0, feat 1..64) ===============
        {
            half8 A[5][2];
            #pragma unroll
            for (int m = 0; m < 5; ++m)
                #pragma unroll
                for (int kc = 0; kc < 2; ++kc)
                    A[m][kc] = *(const half8*)(wt + 4096 + (m * 2 + kc) * 512 + lane * 8);
            #pragma unroll
            for (int n = 0; n < 2; ++n) {
                const int pt = (wv << 5) + (n << 4) + lr;
                const half8 B0 = *(const half8*)(bB + pt * 72 + 0 * 32 + lg * 8);
                const half8 B1 = *(const half8*)(bB + pt * 72 + 1 * 32 + lg * 8);
                #pragma unroll
                for (int m = 0; m < 4; ++m) {
                    f32x4 cr = *(const f32x4*)(sbias + 64 + m * 16 + 4 * lg);
                    cr = __builtin_amdgcn_mfma_f32_16x16x32_f16(A[m][0], B0, cr, 0, 0, 0);
                    cr = __builtin_amdgcn_mfma_f32_16x16x32_f16(A[m][1], B1, cr, 0, 0, 0);
                    half4v o4;
                    #pragma unroll
                    for (int r = 0; r < 4; ++r) o4[r] = (_Float16)fmaxf(cr[r], 0.f);
                    *(half4v*)(aB + pt * 104 + 16 * m + 4 * lg) = o4;   // cols 0..63 (col0 dead)
                    if (m == 0 && lg == 0)
                        out[cbase + pt] = __expf(cr[0]);                // sigma
                }
                {   // m=4: only row 64 (feat index 63) is real
                    f32x4 cr = *(const f32x4*)(sbias + 64 + 4 * 16 + 4 * lg);
                    cr = __builtin_amdgcn_mfma_f32_16x16x32_f16(A[4][0], B0, cr, 0, 0, 0);
                    cr = __builtin_amdgcn_mfma_f32_16x16x32_f16(A[4][1], B1, cr, 0, 0, 0);
                    if (lg == 0) aB[pt * 104 + 64] = (_Float16)fmaxf(cr[0], 0.f);
                }
            }
        }

        // ================= L3: 96 -> 64, relu ==================================
        {
            half8 A[4][3];
            #pragma unroll
            for (int m = 0; m < 4; ++m)
                #pragma unroll
                for (int kc = 0; kc < 3; ++kc)
                    A[m][kc] = *(const half8*)(wt + 9216 + (m * 3 + kc) * 512 + lane * 8);
            #pragma unroll
            for (int n = 0; n < 2; ++n) {
                const int pt = (wv << 5) + (n << 4) + lr;
                const half8 B0 = *(const half8*)(aB + pt * 104 + 0 * 32 + lg * 8);
                const half8 B1 = *(const half8*)(aB + pt * 104 + 1 * 32 + lg * 8);
                const half8 B2 = *(const half8*)(aB + pt * 104 + 2 * 32 + lg * 8);
                #pragma unroll
                for (int m = 0; m < 4; ++m) {
                    f32x4 cr = *(const f32x4*)(sbias + 144 + m * 16 + 4 * lg);
                    cr = __builtin_amdgcn_mfma_f32_16x16x32_f16(A[m][0], B0, cr, 0, 0, 0);
                    cr = __builtin_amdgcn_mfma_f32_16x16x32_f16(A[m][1], B1, cr, 0, 0, 0);
                    cr = __builtin_amdgcn_mfma_f32_16x16x32_f16(A[m][2], B2, cr, 0, 0, 0);
                    half4v o4;
                    #pragma unroll
                    for (int r = 0; r < 4; ++r) o4[r] = (_Float16)fmaxf(cr[r], 0.f);
                    *(half4v*)(bB + pt * 72 + 16 * m + 4 * lg) = o4;
                }
            }
        }

        // ================= L4: 64 -> 3, sigmoid ================================
        {
            const half8 A0 = *(const half8*)(wt + 15360 + 0 * 512 + lane * 8);
            const half8 A1 = *(const half8*)(wt + 15360 + 1 * 512 + lane * 8);
            #pragma unroll
            for (int n = 0; n < 2; ++n) {
                const int pt = (wv << 5) + (n << 4) + lr;
                const half8 B0 = *(const half8*)(bB + pt * 72 + 0 * 32 + lg * 8);
                const half8 B1 = *(const half8*)(bB + pt * 72 + 1 * 32 + lg * 8);
                f32x4 cr = *(const f32x4*)(sbias + 208 + 4 * lg);
                cr = __builtin_amdgcn_mfma_f32_16x16x32_f16(A0, B0, cr, 0, 0, 0);
                cr = __builtin_amdgcn_mfma_f32_16x16x32_f16(A1, B1, cr, 0, 0, 0);
                if (lg == 0) {
                    const int gpt = cbase + pt;
                    #pragma unroll
                    for (int r = 0; r < 3; ++r)
                        out[NPTS + 3 * gpt + r] = 1.0f / (1.0f + __expf(-cr[r]));
                }
            }
        }
    }
}

extern "C" void kernel_launch(void* const* d_in, const int* in_sizes, int n_in,
                              void* d_out, int out_size, void* d_ws, size_t ws_size,
                              hipStream_t stream) {
    const float* x     = (const float*)d_in[0];
    const float* v     = (const float*)d_in[1];
    // d_in[2] = o, unused by the forward pass
    const float* table = (const float*)d_in[3];
    const float* dw1   = (const float*)d_in[4];
    const float* db1   = (const float*)d_in[5];
    const float* dw2   = (const float*)d_in[6];
    const float* db2   = (const float*)d_in[7];
    const float* rw1   = (const float*)d_in[8];
    const float* rb1   = (const float*)d_in[9];
    const float* rw2   = (const float*)d_in[10];
    const float* rb2   = (const float*)d_in[11];
    float* out = (float*)d_out;

    hipLaunchKernelGGL(prep, dim3(65), dim3(256), 0, stream,
                       dw1, db1, dw2, db2, rw1, rb1, rw2, rb2, d_ws);
    hipLaunchKernelGGL(nerf_fwd, dim3(GRID), dim3(THR), 0, stream,
                       x, v, table, (const float*)d_ws, out);
}

// Round 5
// 191.503 us; speedup vs baseline: 3.2348x; 1.0006x over previous
//
#include <hip/hip_runtime.h>

#define NPTS   524288
#define TBLM   ((1u << 19) - 1u)
#define THR    512
#define CHUNK  128
#define CHUNKS 4
#define GRID   (NPTS / (CHUNK * CHUNKS))   // 1024

typedef _Float16 half8  __attribute__((ext_vector_type(8)));
typedef _Float16 half4v __attribute__((ext_vector_type(4)));
typedef float    f32x4  __attribute__((ext_vector_type(4)));

// d_ws layout (halves): W1 frags [m4][kc2][lane64][j8] @0 (4096)
//                       W2 frags [m5][kc2][lane][j]   @4096 (5120)
//                       W3 frags [m4][kc3][lane][j]   @9216 (6144)
//                       W4 frags [kc2][lane][j]       @15360 (1024)
// floats @byte 32768: b1[64], b2[80], b3[64], b4[16]  (224 floats)

__global__ __launch_bounds__(256)
void prep(const float* __restrict__ dw1, const float* __restrict__ db1,
          const float* __restrict__ dw2, const float* __restrict__ db2,
          const float* __restrict__ rw1, const float* __restrict__ rb1,
          const float* __restrict__ rw2, const float* __restrict__ rb2,
          void* __restrict__ ws)
{
    const int t = blockIdx.x * 256 + threadIdx.x;
    if (t < 16384) {
        float w = 0.0f;
        if (t < 4096) {                       // W1: k' permuted (39 dead, grid at 40..47)
            const int u = t, mkc = u >> 9, m = mkc >> 1, kc = mkc & 1;
            const int lane = (u >> 3) & 63, j = u & 7;
            const int row = 16 * m + (lane & 15);
            const int kp  = kc * 32 + (lane >> 4) * 8 + j;
            if (kp < 39)      w = dw1[kp * 64 + row];
            else if (kp == 39) w = 0.0f;
            else if (kp < 48) w = dw1[(kp - 1) * 64 + row];
        } else if (t < 9216) {                // W2
            const int u = t - 4096, mkc = u >> 9, m = mkc >> 1, kc = mkc & 1;
            const int lane = (u >> 3) & 63, j = u & 7;
            const int row = 16 * m + (lane & 15);
            const int k   = kc * 32 + (lane >> 4) * 8 + j;
            if (row < 65) w = dw2[k * 65 + row];
        } else if (t < 15360) {               // W3: col0 dead, feat@1..64, sh3@65..73
            const int u = t - 9216, mkc = u >> 9, m = mkc / 3, kc = mkc - 3 * m;
            const int lane = (u >> 3) & 63, j = u & 7;
            const int row = 16 * m + (lane & 15);
            const int kp  = kc * 32 + (lane >> 4) * 8 + j;
            if (kp >= 1 && kp <= 73) w = rw1[(kp - 1) * 64 + row];
        } else {                              // W4
            const int u = t - 15360, kc = u >> 9;
            const int lane = (u >> 3) & 63, j = u & 7;
            const int row = lane & 15;
            const int k   = kc * 32 + (lane >> 4) * 8 + j;
            if (row < 3) w = rw2[k * 3 + row];
        }
        ((_Float16*)ws)[t] = (_Float16)w;
    } else if (t < 16384 + 224) {
        const int u = t - 16384;
        float b = 0.0f;
        if (u < 64)        b = db1[u];
        else if (u < 144)  { const int r = u - 64;  if (r < 65) b = db2[r]; }
        else if (u < 208)  b = rb1[u - 144];
        else               { const int r = u - 208; if (r < 3)  b = rb2[r]; }
        ((float*)((char*)ws + 32768))[u] = b;
    }
}

__device__ __forceinline__ float sstep(float t) { return t * t * (3.0f - 2.0f * t); }

__global__ __launch_bounds__(THR, 4)
void nerf_fwd(const float* __restrict__ x,
              const float* __restrict__ v,
              const float* __restrict__ table,
              const float* __restrict__ ws,
              float* __restrict__ out)
{
    // LDS: [0,32768) wt halves (frag order) ; [32768,33664) biases f32 ;
    //      [33664,60288) aBuf 128x104 f16  ; [60288,78720) bBuf 128x72 f16
    __shared__ __align__(16) unsigned char smem[78720];
    _Float16* wt    = (_Float16*)smem;
    float*    sbias = (float*)(smem + 32768);
    _Float16* aB    = (_Float16*)(smem + 33664);
    _Float16* bB    = (_Float16*)(smem + 60288);

    const int tid  = threadIdx.x;
    const int lane = tid & 63;
    const int wv   = tid >> 6;       // 8 waves; wave owns points 16wv..16wv+15
    const int lr   = lane & 15;
    const int lg   = lane >> 4;

    // ---- stage weights+biases: one linear coalesced copy (2104 uint4) ----
    {
        const uint4* src = (const uint4*)ws;
        uint4* dst = (uint4*)smem;
        #pragma unroll
        for (int i = 0; i < 5; ++i) {
            const int idx = tid + i * THR;
            if (idx < 2104) dst[idx] = src[idx];
        }
    }
    __syncthreads();   // the only barrier: wt/sbias read-only afterwards

    const int gi0 = blockIdx.x * (CHUNK * CHUNKS);

    for (int c = 0; c < CHUNKS; ++c) {
        const int cbase = gi0 + c * CHUNK;

        // ======== encode: 4 lanes per point (fourier | hash01 | hash23 | sh3) ====
        {
            const int p    = (wv << 4) + (lane >> 2);
            const int gi   = cbase + p;
            const int role = lane & 3;
            _Float16* row = aB + p * 104;
            if (role == 3) {
                // ---- sh3 -> cols 64..73 (col64 placeholder), zeros 48..63, 74..95
                const float v0 = v[3 * gi + 0], v1 = v[3 * gi + 1], v2 = v[3 * gi + 2];
                float sh[9];
                sh[0] = 0.28209479177387814f;
                sh[1] = -0.4886025119029199f * v1;
                sh[2] =  0.4886025119029199f * v2;
                sh[3] = -0.4886025119029199f * v0;
                sh[4] =  1.0925484305920792f * v0 * v1;
                sh[5] = -1.0925484305920792f * v1 * v2;
                sh[6] =  0.9461746957575601f * v2 * v2 - 0.31539156525252005f;
                sh[7] = -1.0925484305920792f * v0 * v2;
                sh[8] =  0.5462742152960396f * (v0 * v0 - v1 * v1);
                half8 s0, s1, z;
                s0[0] = (_Float16)0.f;
                #pragma unroll
                for (int i = 0; i < 7; ++i) s0[i + 1] = (_Float16)sh[i];
                s1[0] = (_Float16)sh[7]; s1[1] = (_Float16)sh[8];
                #pragma unroll
                for (int i = 2; i < 8; ++i) s1[i] = (_Float16)0.f;
                #pragma unroll
                for (int i = 0; i < 8; ++i) z[i] = (_Float16)0.f;
                *(half8*)(row + 48) = z;
                *(half8*)(row + 56) = z;
                *(half8*)(row + 64) = s0;
                *(half8*)(row + 72) = s1;
                *(half8*)(row + 80) = z;
                *(half8*)(row + 88) = z;
            } else {
                const float x0 = x[3 * gi + 0], x1 = x[3 * gi + 1], x2 = x[3 * gi + 2];
                if (role == 0) {
                    // ---- xyz + fourier -> cols 0..39 (39 dead=0) ----
                    float e[40];
                    e[0] = x0; e[1] = x1; e[2] = x2;
                    const float a[3] = {x0, x1, x2};
                    #pragma unroll
                    for (int d = 0; d < 3; ++d)
                        #pragma unroll
                        for (int f = 0; f < 6; ++f) {
                            const float ang = a[d] * (float)(1 << f);
                            e[3 + d * 12 + f]     = __sinf(ang);
                            e[3 + d * 12 + 6 + f] = __cosf(ang);
                        }
                    e[39] = 0.0f;
                    #pragma unroll
                    for (int chk = 0; chk < 5; ++chk) {
                        half8 h;
                        #pragma unroll
                        for (int i = 0; i < 8; ++i) h[i] = (_Float16)e[chk * 8 + i];
                        *(half8*)(row + chk * 8) = h;
                    }
                } else {
                    // ---- hash: role1 -> levels 0,1 (cols 40..43); role2 -> 2,3 (44..47)
                    const float u0 = (x0 + 1.0f) * 0.5f, u1 = (x1 + 1.0f) * 0.5f, u2 = (x2 + 1.0f) * 0.5f;
                    const float rfA = (role == 1) ? 33.0f : 56.0f;
                    const float rfB = (role == 1) ? 43.0f : 74.0f;
                    const unsigned lvA = (role == 1) ? 0u : 2u;
                    float g[4];
                    #pragma unroll
                    for (int s = 0; s < 2; ++s) {
                        const float rf = s ? rfB : rfA;
                        const unsigned lv = lvA + (unsigned)s;
                        const float px = u0 * rf, py = u1 * rf, pz = u2 * rf;
                        const float fx = floorf(px), fy = floorf(py), fz = floorf(pz);
                        const float wx = sstep(px - fx), wy = sstep(py - fy), wz = sstep(pz - fz);
                        const unsigned cx = (unsigned)fx, cy = (unsigned)fy, cz = (unsigned)fz;
                        float g0 = 0.f, g1 = 0.f;
                        #pragma unroll
                        for (int cc = 0; cc < 8; ++cc) {
                            const unsigned hx = cx + (cc & 1);
                            const unsigned hy = cy + ((cc >> 1) & 1);
                            const unsigned hz = cz + ((cc >> 2) & 1);
                            const unsigned hh = (hx ^ (hy * 2654435761u) ^ (hz * 805459861u)) & TBLM;
                            const float2 tv = *reinterpret_cast<const float2*>(
                                table + (lv * (TBLM + 1u) + hh) * 2u);
                            const float cw = ((cc & 1) ? wx : 1.0f - wx) *
                                             ((cc & 2) ? wy : 1.0f - wy) *
                                             ((cc & 4) ? wz : 1.0f - wz);
                            g0 = fmaf(cw, tv.x, g0);
                            g1 = fmaf(cw, tv.y, g1);
                        }
                        g[2 * s]     = g0;
                        g[2 * s + 1] = g1;
                    }
                    half4v h4;
                    #pragma unroll
                    for (int i = 0; i < 4; ++i) h4[i] = (_Float16)g[i];
                    *(half4v*)(row + 40 + (role - 1) * 4) = h4;
                }
            }
        }

        const int pt = (wv << 4) + lr;   // this wave's point rows

        // ================= L1: 64 -> 64, relu ==================================
        {
            const half8 B0 = *(const half8*)(aB + pt * 104 + 0 * 32 + lg * 8);
            const half8 B1 = *(const half8*)(aB + pt * 104 + 1 * 32 + lg * 8);
            #pragma unroll
            for (int m = 0; m < 4; ++m) {
                const half8 A0 = *(const half8*)(wt + (m * 2 + 0) * 512 + lane * 8);
                const half8 A1 = *(const half8*)(wt + (m * 2 + 1) * 512 + lane * 8);
                f32x4 cr = *(const f32x4*)(sbias + 0 + m * 16 + 4 * lg);
                cr = __builtin_amdgcn_mfma_f32_16x16x32_f16(A0, B0, cr, 0, 0, 0);
                cr = __builtin_amdgcn_mfma_f32_16x16x32_f16(A1, B1, cr, 0, 0, 0);
                half4v o4;
                #pragma unroll
                for (int r = 0; r < 4; ++r) o4[r] = (_Float16)fmaxf(cr[r], 0.f);
                *(half4v*)(bB + pt * 72 + 16 * m + 4 * lg) = o4;
            }
        }

        // ================= L2: 64 -> 65 (sigma row0, feat 1..64) ===============
        {
            const half8 B0 = *(const half8*)(bB + pt * 72 + 0 * 32 + lg * 8);
            const half8 B1 = *(const half8*)(bB + pt * 72 + 1 * 32 + lg * 8);
            #pragma unroll
            for (int m = 0; m < 4; ++m) {
                const half8 A0 = *(const half8*)(wt + 4096 + (m * 2 + 0) * 512 + lane * 8);
                const half8 A1 = *(const half8*)(wt + 4096 + (m * 2 + 1) * 512 + lane * 8);
                f32x4 cr = *(const f32x4*)(sbias + 64 + m * 16 + 4 * lg);
                cr = __builtin_amdgcn_mfma_f32_16x16x32_f16(A0, B0, cr, 0, 0, 0);
                cr = __builtin_amdgcn_mfma_f32_16x16x32_f16(A1, B1, cr, 0, 0, 0);
                half4v o4;
                #pragma unroll
                for (int r = 0; r < 4; ++r) o4[r] = (_Float16)fmaxf(cr[r], 0.f);
                *(half4v*)(aB + pt * 104 + 16 * m + 4 * lg) = o4;   // cols 0..63 (col0 dead)
                if (m == 0 && lg == 0)
                    out[cbase + pt] = __expf(cr[0]);                // sigma
            }
            {   // m=4: only row 64 (feat index 63) is real
                const half8 A0 = *(const half8*)(wt + 4096 + (4 * 2 + 0) * 512 + lane * 8);
                const half8 A1 = *(const half8*)(wt + 4096 + (4 * 2 + 1) * 512 + lane * 8);
                f32x4 cr = *(const f32x4*)(sbias + 64 + 4 * 16 + 4 * lg);
                cr = __builtin_amdgcn_mfma_f32_16x16x32_f16(A0, B0, cr, 0, 0, 0);
                cr = __builtin_amdgcn_mfma_f32_16x16x32_f16(A1, B1, cr, 0, 0, 0);
                if (lg == 0) aB[pt * 104 + 64] = (_Float16)fmaxf(cr[0], 0.f);
            }
        }

        // ================= L3: 96 -> 64, relu ==================================
        {
            const half8 B0 = *(const half8*)(aB + pt * 104 + 0 * 32 + lg * 8);
            const half8 B1 = *(const half8*)(aB + pt * 104 + 1 * 32 + lg * 8);
            const half8 B2 = *(const half8*)(aB + pt * 104 + 2 * 32 + lg * 8);
            #pragma unroll
            for (int m = 0; m < 4; ++m) {
                const half8 A0 = *(const half8*)(wt + 9216 + (m * 3 + 0) * 512 + lane * 8);
                const half8 A1 = *(const half8*)(wt + 9216 + (m * 3 + 1) * 512 + lane * 8);
                const half8 A2 = *(const half8*)(wt + 9216 + (m * 3 + 2) * 512 + lane * 8);
                f32x4 cr = *(const f32x4*)(sbias + 144 + m * 16 + 4 * lg);
                cr = __builtin_amdgcn_mfma_f32_16x16x32_f16(A0, B0, cr, 0, 0, 0);
                cr = __builtin_amdgcn_mfma_f32_16x16x32_f16(A1, B1, cr, 0, 0, 0);
                cr = __builtin_amdgcn_mfma_f32_16x16x32_f16(A2, B2, cr, 0, 0, 0);
                half4v o4;
                #pragma unroll
                for (int r = 0; r < 4; ++r) o4[r] = (_Float16)fmaxf(cr[r], 0.f);
                *(half4v*)(bB + pt * 72 + 16 * m + 4 * lg) = o4;
            }
        }

        // ================= L4: 64 -> 3, sigmoid ================================
        {
            const half8 A0 = *(const half8*)(wt + 15360 + 0 * 512 + lane * 8);
            const half8 A1 = *(const half8*)(wt + 15360 + 1 * 512 + lane * 8);
            const half8 B0 = *(const half8*)(bB + pt * 72 + 0 * 32 + lg * 8);
            const half8 B1 = *(const half8*)(bB + pt * 72 + 1 * 32 + lg * 8);
            f32x4 cr = *(const f32x4*)(sbias + 208 + 4 * lg);
            cr = __builtin_amdgcn_mfma_f32_16x16x32_f16(A0, B0, cr, 0, 0, 0);
            cr = __builtin_amdgcn_mfma_f32_16x16x32_f16(A1, B1, cr, 0, 0, 0);
            if (lg == 0) {
                const int gpt = cbase + pt;
                #pragma unroll
                for (int r = 0; r < 3; ++r)
                    out[NPTS + 3 * gpt + r] = 1.0f / (1.0f + __expf(-cr[r]));
            }
        }
    }
}

extern "C" void kernel_launch(void* const* d_in, const int* in_sizes, int n_in,
                              void* d_out, int out_size, void* d_ws, size_t ws_size,
                              hipStream_t stream) {
    const float* x     = (const float*)d_in[0];
    const float* v     = (const float*)d_in[1];
    // d_in[2] = o, unused by the forward pass
    const float* table = (const float*)d_in[3];
    const float* dw1   = (const float*)d_in[4];
    const float* db1   = (const float*)d_in[5];
    const float* dw2   = (const float*)d_in[6];
    const float* db2   = (const float*)d_in[7];
    const float* rw1   = (const float*)d_in[8];
    const float* rb1   = (const float*)d_in[9];
    const float* rw2   = (const float*)d_in[10];
    const float* rb2   = (const float*)d_in[11];
    float* out = (float*)d_out;

    hipLaunchKernelGGL(prep, dim3(65), dim3(256), 0, stream,
                       dw1, db1, dw2, db2, rw1, rb1, rw2, rb2, d_ws);
    hipLaunchKernelGGL(nerf_fwd, dim3(GRID), dim3(THR), 0, stream,
                       x, v, table, (const float*)d_ws, out);
}

// Round 6
// 187.842 us; speedup vs baseline: 3.2979x; 1.0195x over previous
//
#include <hip/hip_runtime.h>

#define NPTS   524288
#define TBLM   ((1u << 19) - 1u)
#define THR    512
#define CHUNK  128
#define CHUNKS 4
#define GRID   (NPTS / (CHUNK * CHUNKS))   // 1024

typedef _Float16 half8  __attribute__((ext_vector_type(8)));
typedef _Float16 half4v __attribute__((ext_vector_type(4)));
typedef _Float16 half2v __attribute__((ext_vector_type(2)));
typedef float    f32x4  __attribute__((ext_vector_type(4)));

// d_ws layout (halves): W1 frags [m4][kc2][lane64][j8] @0 (4096)
//                       W2 frags [m5][kc2][lane][j]   @4096 (5120)
//                       W3 frags [m4][kc3][lane][j]   @9216 (6144)
//                       W4 frags [kc2][lane][j]       @15360 (1024)
// floats @byte 32768: b1[64], b2[80], b3[64], b4[16]  (224 floats)

__global__ __launch_bounds__(256)
void prep(const float* __restrict__ dw1, const float* __restrict__ db1,
          const float* __restrict__ dw2, const float* __restrict__ db2,
          const float* __restrict__ rw1, const float* __restrict__ rb1,
          const float* __restrict__ rw2, const float* __restrict__ rb2,
          void* __restrict__ ws)
{
    const int t = blockIdx.x * 256 + threadIdx.x;
    if (t < 16384) {
        float w = 0.0f;
        if (t < 4096) {                       // W1: k' permuted (39 dead, grid at 40..47)
            const int u = t, mkc = u >> 9, m = mkc >> 1, kc = mkc & 1;
            const int lane = (u >> 3) & 63, j = u & 7;
            const int row = 16 * m + (lane & 15);
            const int kp  = kc * 32 + (lane >> 4) * 8 + j;
            if (kp < 39)      w = dw1[kp * 64 + row];
            else if (kp == 39) w = 0.0f;
            else if (kp < 48) w = dw1[(kp - 1) * 64 + row];
        } else if (t < 9216) {                // W2
            const int u = t - 4096, mkc = u >> 9, m = mkc >> 1, kc = mkc & 1;
            const int lane = (u >> 3) & 63, j = u & 7;
            const int row = 16 * m + (lane & 15);
            const int k   = kc * 32 + (lane >> 4) * 8 + j;
            if (row < 65) w = dw2[k * 65 + row];
        } else if (t < 15360) {               // W3: col0 dead, feat@1..64, sh3@65..73
            const int u = t - 9216, mkc = u >> 9, m = mkc / 3, kc = mkc - 3 * m;
            const int lane = (u >> 3) & 63, j = u & 7;
            const int row = 16 * m + (lane & 15);
            const int kp  = kc * 32 + (lane >> 4) * 8 + j;
            if (kp >= 1 && kp <= 73) w = rw1[(kp - 1) * 64 + row];
        } else {                              // W4
            const int u = t - 15360, kc = u >> 9;
            const int lane = (u >> 3) & 63, j = u & 7;
            const int row = lane & 15;
            const int k   = kc * 32 + (lane >> 4) * 8 + j;
            if (row < 3) w = rw2[k * 3 + row];
        }
        ((_Float16*)ws)[t] = (_Float16)w;
    } else if (t < 16384 + 224) {
        const int u = t - 16384;
        float b = 0.0f;
        if (u < 64)        b = db1[u];
        else if (u < 144)  { const int r = u - 64;  if (r < 65) b = db2[r]; }
        else if (u < 208)  b = rb1[u - 144];
        else               { const int r = u - 208; if (r < 3)  b = rb2[r]; }
        ((float*)((char*)ws + 32768))[u] = b;
    }
}

__device__ __forceinline__ float sstep(float t) { return t * t * (3.0f - 2.0f * t); }

// Per-lane pipelined gather state (all members statically addressed -> registers).
struct GS {
    float  x0, x1, x2, v0, v1, v2;
    float  ax, ay, az;
    float2 t0, t1, t2, t3, t4, t5, t6, t7;
};

__device__ __forceinline__ void gather_issue(int gi, int role,
    const float* __restrict__ x, const float* __restrict__ v,
    const float* __restrict__ table, GS& s)
{
    s.x0 = x[3 * gi + 0]; s.x1 = x[3 * gi + 1]; s.x2 = x[3 * gi + 2];
    if (role == 1) { s.v0 = v[3 * gi + 0]; s.v1 = v[3 * gi + 1]; s.v2 = v[3 * gi + 2]; }
    const float rf = (role == 0) ? 33.f : (role == 1) ? 43.f : (role == 2) ? 56.f : 74.f;
    const float u0 = (s.x0 + 1.f) * 0.5f, u1 = (s.x1 + 1.f) * 0.5f, u2 = (s.x2 + 1.f) * 0.5f;
    const float px = u0 * rf, py = u1 * rf, pz = u2 * rf;
    const float fx = floorf(px), fy = floorf(py), fz = floorf(pz);
    s.ax = sstep(px - fx); s.ay = sstep(py - fy); s.az = sstep(pz - fz);
    const unsigned cx = (unsigned)fx, cy = (unsigned)fy, cz = (unsigned)fz;
    const float* tb = table + (unsigned)role * (TBLM + 1u) * 2u;
    const unsigned hy0 = cy * 2654435761u, hy1 = (cy + 1u) * 2654435761u;
    const unsigned hz0 = cz * 805459861u,  hz1 = (cz + 1u) * 805459861u;
#define LDC(dst, HX, HY, HZ) { const unsigned hh = ((HX) ^ (HY) ^ (HZ)) & TBLM; \
                               dst = *reinterpret_cast<const float2*>(tb + hh * 2u); }
    LDC(s.t0, cx,      hy0, hz0);
    LDC(s.t1, cx + 1u, hy0, hz0);
    LDC(s.t2, cx,      hy1, hz0);
    LDC(s.t3, cx + 1u, hy1, hz0);
    LDC(s.t4, cx,      hy0, hz1);
    LDC(s.t5, cx + 1u, hy0, hz1);
    LDC(s.t6, cx,      hy1, hz1);
    LDC(s.t7, cx + 1u, hy1, hz1);
#undef LDC
}

__device__ __forceinline__ void encode_finish(const GS& s, int role, _Float16* row)
{
    // trilinear-smoothstep interpolation of the 8 gathered entries
    const float ax = s.ax, ay = s.ay, az = s.az;
    const float bx = 1.f - ax, by = 1.f - ay, bz = 1.f - az;
    const float p00 = bx * by, p10 = ax * by, p01 = bx * ay, p11 = ax * ay;
    const float w0 = p00 * bz, w1 = p10 * bz, w2 = p01 * bz, w3 = p11 * bz;
    const float w4 = p00 * az, w5 = p10 * az, w6 = p01 * az, w7 = p11 * az;
    float g0 = w0 * s.t0.x, g1 = w0 * s.t0.y;
    g0 = fmaf(w1, s.t1.x, g0); g1 = fmaf(w1, s.t1.y, g1);
    g0 = fmaf(w2, s.t2.x, g0); g1 = fmaf(w2, s.t2.y, g1);
    g0 = fmaf(w3, s.t3.x, g0); g1 = fmaf(w3, s.t3.y, g1);
    g0 = fmaf(w4, s.t4.x, g0); g1 = fmaf(w4, s.t4.y, g1);
    g0 = fmaf(w5, s.t5.x, g0); g1 = fmaf(w5, s.t5.y, g1);
    g0 = fmaf(w6, s.t6.x, g0); g1 = fmaf(w6, s.t6.y, g1);
    g0 = fmaf(w7, s.t7.x, g0); g1 = fmaf(w7, s.t7.y, g1);
    half2v gh; gh[0] = (_Float16)g0; gh[1] = (_Float16)g1;
    *(half2v*)(row + 40 + 2 * role) = gh;      // grid feats, cols 40..47

    if (role == 0) {
        // xyz + fourier -> cols 0..39 (col 39 dead = 0)
        float e[40];
        e[0] = s.x0; e[1] = s.x1; e[2] = s.x2;
        const float a[3] = {s.x0, s.x1, s.x2};
        #pragma unroll
        for (int d = 0; d < 3; ++d)
            #pragma unroll
            for (int f = 0; f < 6; ++f) {
                const float ang = a[d] * (float)(1 << f);
                e[3 + d * 12 + f]     = __sinf(ang);
                e[3 + d * 12 + 6 + f] = __cosf(ang);
            }
        e[39] = 0.0f;
        #pragma unroll
        for (int chk = 0; chk < 5; ++chk) {
            half8 h;
            #pragma unroll
            for (int i = 0; i < 8; ++i) h[i] = (_Float16)e[chk * 8 + i];
            *(half8*)(row + chk * 8) = h;
        }
    } else if (role == 1) {
        // sh3 -> cols 64..79 (col 64 placeholder, L2 overwrites with feat63)
        const float v0 = s.v0, v1 = s.v1, v2 = s.v2;
        float sh[9];
        sh[0] = 0.28209479177387814f;
        sh[1] = -0.4886025119029199f * v1;
        sh[2] =  0.4886025119029199f * v2;
        sh[3] = -0.4886025119029199f * v0;
        sh[4] =  1.0925484305920792f * v0 * v1;
        sh[5] = -1.0925484305920792f * v1 * v2;
        sh[6] =  0.9461746957575601f * v2 * v2 - 0.31539156525252005f;
        sh[7] = -1.0925484305920792f * v0 * v2;
        sh[8] =  0.5462742152960396f * (v0 * v0 - v1 * v1);
        half8 s0, s1;
        s0[0] = (_Float16)0.f;
        #pragma unroll
        for (int i = 0; i < 7; ++i) s0[i + 1] = (_Float16)sh[i];
        s1[0] = (_Float16)sh[7]; s1[1] = (_Float16)sh[8];
        #pragma unroll
        for (int i = 2; i < 8; ++i) s1[i] = (_Float16)0.f;
        *(half8*)(row + 64) = s0;
        *(half8*)(row + 72) = s1;
    } else if (role == 2) {
        half8 z;
        #pragma unroll
        for (int i = 0; i < 8; ++i) z[i] = (_Float16)0.f;
        *(half8*)(row + 48) = z;
        *(half8*)(row + 56) = z;
    } else {
        half8 z;
        #pragma unroll
        for (int i = 0; i < 8; ++i) z[i] = (_Float16)0.f;
        *(half8*)(row + 80) = z;
        *(half8*)(row + 88) = z;
    }
}

__global__ __launch_bounds__(THR, 4)
void nerf_fwd(const float* __restrict__ x,
              const float* __restrict__ v,
              const float* __restrict__ table,
              const float* __restrict__ ws,
              float* __restrict__ out)
{
    // LDS: [0,32768) wt halves (frag order) ; [32768,33664) biases f32 ;
    //      [33664,60288) aBuf 128x104 f16  ; [60288,78720) bBuf 128x72 f16
    __shared__ __align__(16) unsigned char smem[78720];
    _Float16* wt    = (_Float16*)smem;
    float*    sbias = (float*)(smem + 32768);
    _Float16* aB    = (_Float16*)(smem + 33664);
    _Float16* bB    = (_Float16*)(smem + 60288);

    const int tid  = threadIdx.x;
    const int lane = tid & 63;
    const int wv   = tid >> 6;       // 8 waves; wave owns points 16wv..16wv+15
    const int lr   = lane & 15;
    const int lg   = lane >> 4;
    const int role = lane & 3;
    const int ep   = (wv << 4) + (lane >> 2);   // encode point row (wave-private)
    const int gi0  = blockIdx.x * (CHUNK * CHUNKS);

    GS cur, nxt;
    // chunk-0 gathers go in flight; latency hides under weight staging + barrier
    gather_issue(gi0 + ep, role, x, v, table, cur);

    // ---- stage weights+biases: one linear coalesced copy (2104 uint4) ----
    {
        const uint4* src = (const uint4*)ws;
        uint4* dst = (uint4*)smem;
        #pragma unroll
        for (int i = 0; i < 5; ++i) {
            const int idx = tid + i * THR;
            if (idx < 2104) dst[idx] = src[idx];
        }
    }
    __syncthreads();   // the only barrier: wt/sbias read-only afterwards

    const int pt = (wv << 4) + lr;   // this wave's point rows in the MLP

    #pragma unroll
    for (int c = 0; c < CHUNKS; ++c) {
        const int cbase = gi0 + c * CHUNK;

        // finish encode for chunk c (consumes in-flight gathers)
        encode_finish(cur, role, aB + ep * 104);

        // issue chunk c+1 gathers BEFORE the MLP: latency hides under MFMA/DS
        if (c + 1 < CHUNKS)
            gather_issue(gi0 + (c + 1) * CHUNK + ep, role, x, v, table, nxt);

        // ================= L1: 64 -> 64, relu ==================================
        {
            const half8 B0 = *(const half8*)(aB + pt * 104 + 0 * 32 + lg * 8);
            const half8 B1 = *(const half8*)(aB + pt * 104 + 1 * 32 + lg * 8);
            #pragma unroll
            for (int m = 0; m < 4; ++m) {
                const half8 A0 = *(const half8*)(wt + (m * 2 + 0) * 512 + lane * 8);
                const half8 A1 = *(const half8*)(wt + (m * 2 + 1) * 512 + lane * 8);
                f32x4 cr = *(const f32x4*)(sbias + 0 + m * 16 + 4 * lg);
                cr = __builtin_amdgcn_mfma_f32_16x16x32_f16(A0, B0, cr, 0, 0, 0);
                cr = __builtin_amdgcn_mfma_f32_16x16x32_f16(A1, B1, cr, 0, 0, 0);
                half4v o4;
                #pragma unroll
                for (int r = 0; r < 4; ++r) o4[r] = (_Float16)fmaxf(cr[r], 0.f);
                *(half4v*)(bB + pt * 72 + 16 * m + 4 * lg) = o4;
            }
        }

        // ================= L2: 64 -> 65 (sigma row0, feat 1..64) ===============
        {
            const half8 B0 = *(const half8*)(bB + pt * 72 + 0 * 32 + lg * 8);
            const half8 B1 = *(const half8*)(bB + pt * 72 + 1 * 32 + lg * 8);
            #pragma unroll
            for (int m = 0; m < 4; ++m) {
                const half8 A0 = *(const half8*)(wt + 4096 + (m * 2 + 0) * 512 + lane * 8);
                const half8 A1 = *(const half8*)(wt + 4096 + (m * 2 + 1) * 512 + lane * 8);
                f32x4 cr = *(const f32x4*)(sbias + 64 + m * 16 + 4 * lg);
                cr = __builtin_amdgcn_mfma_f32_16x16x32_f16(A0, B0, cr, 0, 0, 0);
                cr = __builtin_amdgcn_mfma_f32_16x16x32_f16(A1, B1, cr, 0, 0, 0);
                half4v o4;
                #pragma unroll
                for (int r = 0; r < 4; ++r) o4[r] = (_Float16)fmaxf(cr[r], 0.f);
                *(half4v*)(aB + pt * 104 + 16 * m + 4 * lg) = o4;   // cols 0..63 (col0 dead)
                if (m == 0 && lg == 0)
                    out[cbase + pt] = __expf(cr[0]);                // sigma
            }
            {   // m=4: only row 64 (feat index 63) is real
                const half8 A0 = *(const half8*)(wt + 4096 + (4 * 2 + 0) * 512 + lane * 8);
                const half8 A1 = *(const half8*)(wt + 4096 + (4 * 2 + 1) * 512 + lane * 8);
                f32x4 cr = *(const f32x4*)(sbias + 64 + 4 * 16 + 4 * lg);
                cr = __builtin_amdgcn_mfma_f32_16x16x32_f16(A0, B0, cr, 0, 0, 0);
                cr = __builtin_amdgcn_mfma_f32_16x16x32_f16(A1, B1, cr, 0, 0, 0);
                if (lg == 0) aB[pt * 104 + 64] = (_Float16)fmaxf(cr[0], 0.f);
            }
        }

        // ================= L3: 96 -> 64, relu ==================================
        {
            const half8 B0 = *(const half8*)(aB + pt * 104 + 0 * 32 + lg * 8);
            const half8 B1 = *(const half8*)(aB + pt * 104 + 1 * 32 + lg * 8);
            const half8 B2 = *(const half8*)(aB + pt * 104 + 2 * 32 + lg * 8);
            #pragma unroll
            for (int m = 0; m < 4; ++m) {
                const half8 A0 = *(const half8*)(wt + 9216 + (m * 3 + 0) * 512 + lane * 8);
                const half8 A1 = *(const half8*)(wt + 9216 + (m * 3 + 1) * 512 + lane * 8);
                const half8 A2 = *(const half8*)(wt + 9216 + (m * 3 + 2) * 512 + lane * 8);
                f32x4 cr = *(const f32x4*)(sbias + 144 + m * 16 + 4 * lg);
                cr = __builtin_amdgcn_mfma_f32_16x16x32_f16(A0, B0, cr, 0, 0, 0);
                cr = __builtin_amdgcn_mfma_f32_16x16x32_f16(A1, B1, cr, 0, 0, 0);
                cr = __builtin_amdgcn_mfma_f32_16x16x32_f16(A2, B2, cr, 0, 0, 0);
                half4v o4;
                #pragma unroll
                for (int r = 0; r < 4; ++r) o4[r] = (_Float16)fmaxf(cr[r], 0.f);
                *(half4v*)(bB + pt * 72 + 16 * m + 4 * lg) = o4;
            }
        }

        // ================= L4: 64 -> 3, sigmoid ================================
        {
            const half8 A0 = *(const half8*)(wt + 15360 + 0 * 512 + lane * 8);
            const half8 A1 = *(const half8*)(wt + 15360 + 1 * 512 + lane * 8);
            const half8 B0 = *(const half8*)(bB + pt * 72 + 0 * 32 + lg * 8);
            const half8 B1 = *(const half8*)(bB + pt * 72 + 1 * 32 + lg * 8);
            f32x4 cr = *(const f32x4*)(sbias + 208 + 4 * lg);
            cr = __builtin_amdgcn_mfma_f32_16x16x32_f16(A0, B0, cr, 0, 0, 0);
            cr = __builtin_amdgcn_mfma_f32_16x16x32_f16(A1, B1, cr, 0, 0, 0);
            if (lg == 0) {
                const int gpt = cbase + pt;
                #pragma unroll
                for (int r = 0; r < 3; ++r)
                    out[NPTS + 3 * gpt + r] = 1.0f / (1.0f + __expf(-cr[r]));
            }
        }

        if (c + 1 < CHUNKS) cur = nxt;
    }
}

extern "C" void kernel_launch(void* const* d_in, const int* in_sizes, int n_in,
                              void* d_out, int out_size, void* d_ws, size_t ws_size,
                              hipStream_t stream) {
    const float* x     = (const float*)d_in[0];
    const float* v     = (const float*)d_in[1];
    // d_in[2] = o, unused by the forward pass
    const float* table = (const float*)d_in[3];
    const float* dw1   = (const float*)d_in[4];
    const float* db1   = (const float*)d_in[5];
    const float* dw2   = (const float*)d_in[6];
    const float* db2   = (const float*)d_in[7];
    const float* rw1   = (const float*)d_in[8];
    const float* rb1   = (const float*)d_in[9];
    const float* rw2   = (const float*)d_in[10];
    const float* rb2   = (const float*)d_in[11];
    float* out = (float*)d_out;

    hipLaunchKernelGGL(prep, dim3(65), dim3(256), 0, stream,
                       dw1, db1, dw2, db2, rw1, rb1, rw2, rb2, d_ws);
    hipLaunchKernelGGL(nerf_fwd, dim3(GRID), dim3(THR), 0, stream,
                       x, v, table, (const float*)d_ws, out);
}